// Round 1
// baseline (116.184 us; speedup 1.0000x reference)
//
#include <hip/hip_runtime.h>
#include <math.h>

#define NTOK 8192
#define HID  4096
#define NEXP 64
#define TOPK 8

// tile geometry
constexpr int TOKB = 32;          // tokens per block
constexpr int KC   = 32;          // k-chunk staged per iteration
constexpr int KP   = HID / 4;     // k-range per wave (4 waves split K) = 1024
constexpr int NCH  = KP / KC;     // 32 chunks

__global__ __launch_bounds__(256, 1)
void moe_gate_kernel(const float* __restrict__ Hm, const float* __restrict__ Wm,
                     float* __restrict__ out)
{
    // per-wave staging region: 3072 floats = hT[32k][32tok] (1024) + wT[32k][64e] (2048)
    __shared__ float lds[4 * 3072];

    const int tid  = threadIdx.x;
    const int wave = tid >> 6;
    const int lane = tid & 63;
    const int q    = lane & 7;    // k-quad slot (staging)
    const int g    = lane >> 3;   // row group   (staging)
    const int tm   = lane >> 3;   // token group (compute): tokens tm*4 .. tm*4+3
    const int tn   = lane & 7;    // expert group (compute): experts tn*8 .. tn*8+7

    float* ldsw = lds + wave * 3072;
    const int tok0 = blockIdx.x * TOKB;
    const int kw   = wave * KP;

    const float* hp = Hm + (size_t)(tok0 + g) * HID + kw + q * 4;
    const float* wp = Wm + (size_t)g * HID + kw + q * 4;

    float4 hreg[4];
    float4 wreg[8];

    // prefetch chunk 0
#pragma unroll
    for (int r = 0; r < 4; ++r) hreg[r] = *(const float4*)(hp + (size_t)r * 8 * HID);
#pragma unroll
    for (int r = 0; r < 8; ++r) wreg[r] = *(const float4*)(wp + (size_t)r * 8 * HID);

    float acc[4][8];
#pragma unroll
    for (int i = 0; i < 4; ++i)
#pragma unroll
        for (int j = 0; j < 8; ++j) acc[i][j] = 0.f;

    for (int c = 0; c < NCH; ++c) {
        // ---- stage regs -> LDS (transposed, XOR-swizzled: col ^= (k>>2)<<2) ----
#pragma unroll
        for (int r = 0; r < 4; ++r) {
            const int tk = g + 8 * r;
            float v[4] = {hreg[r].x, hreg[r].y, hreg[r].z, hreg[r].w};
#pragma unroll
            for (int j = 0; j < 4; ++j) {
                const int kl = q * 4 + j;
                ldsw[kl * 32 + (tk ^ (q << 2))] = v[j];
            }
        }
#pragma unroll
        for (int r = 0; r < 8; ++r) {
            const int e = g + 8 * r;
            float v[4] = {wreg[r].x, wreg[r].y, wreg[r].z, wreg[r].w};
#pragma unroll
            for (int j = 0; j < 4; ++j) {
                const int kl = q * 4 + j;
                ldsw[1024 + kl * 64 + (e ^ (q << 2))] = v[j];
            }
        }

        // ---- prefetch next chunk (wraps harmlessly on last iter) ----
        const int cn = (c + 1 == NCH) ? 0 : c + 1;
        {
            const float* hpn = hp + cn * KC;
            const float* wpn = wp + cn * KC;
#pragma unroll
            for (int r = 0; r < 4; ++r) hreg[r] = *(const float4*)(hpn + (size_t)r * 8 * HID);
#pragma unroll
            for (int r = 0; r < 8; ++r) wreg[r] = *(const float4*)(wpn + (size_t)r * 8 * HID);
        }

        // ---- compute: 32 k-steps, 32 FMA each ----
#pragma unroll
        for (int kq = 0; kq < 8; ++kq) {
            const int s = kq << 2;
#pragma unroll
            for (int j = 0; j < 4; ++j) {
                const int kl = kq * 4 + j;
                const float4 hv = *(const float4*)&ldsw[kl * 32 + ((tm * 4) ^ s)];
                const float4 w0 = *(const float4*)&ldsw[1024 + kl * 64 + ((tn * 8) ^ s)];
                const float4 w1 = *(const float4*)&ldsw[1024 + kl * 64 + (((tn * 8) + 4) ^ s)];
                const float hvv[4] = {hv.x, hv.y, hv.z, hv.w};
                const float wvv[8] = {w0.x, w0.y, w0.z, w0.w, w1.x, w1.y, w1.z, w1.w};
#pragma unroll
                for (int i = 0; i < 4; ++i)
#pragma unroll
                    for (int jj = 0; jj < 8; ++jj)
                        acc[i][jj] = fmaf(hvv[i], wvv[jj], acc[i][jj]);
            }
        }
    }

    // ---- write per-wave partials into own region (no barrier needed: own region) ----
#pragma unroll
    for (int i = 0; i < 4; ++i) {
#pragma unroll
        for (int jq = 0; jq < 2; ++jq) {
            float4 v = make_float4(acc[i][jq * 4 + 0], acc[i][jq * 4 + 1],
                                   acc[i][jq * 4 + 2], acc[i][jq * 4 + 3]);
            *(float4*)&ldsw[(tm * 4 + i) * 64 + tn * 8 + jq * 4] = v;
        }
    }
    __syncthreads();

    // ---- softmax + top-8 : lane = expert, each wave handles 8 tokens ----
    float* outw = out;
    float* outi = out + (size_t)NTOK * TOPK;

    for (int t = 0; t < 8; ++t) {
        const int tokL = wave * 8 + t;
        float logit = lds[0 * 3072 + tokL * 64 + lane]
                    + lds[1 * 3072 + tokL * 64 + lane]
                    + lds[2 * 3072 + tokL * 64 + lane]
                    + lds[3 * 3072 + tokL * 64 + lane];

        float m = logit;
#pragma unroll
        for (int off = 32; off; off >>= 1) m = fmaxf(m, __shfl_xor(m, off));
        const float p = expf(logit - m);
        float ssum = p;
#pragma unroll
        for (int off = 32; off; off >>= 1) ssum += __shfl_xor(ssum, off);
        float v = p / ssum;

        const size_t tok = (size_t)(tok0 + tokL);
#pragma unroll
        for (int kk = 0; kk < TOPK; ++kk) {
            float bv = v;
            int   bi = lane;
#pragma unroll
            for (int off = 32; off; off >>= 1) {
                const float ov = __shfl_xor(bv, off);
                const int   oi = __shfl_xor(bi, off);
                if (ov > bv || (ov == bv && oi < bi)) { bv = ov; bi = oi; }
            }
            if (lane == kk) {
                outw[tok * TOPK + kk] = bv;
                outi[tok * TOPK + kk] = (float)bi;
            }
            if (lane == bi) v = -INFINITY;
        }
    }
}

extern "C" void kernel_launch(void* const* d_in, const int* in_sizes, int n_in,
                              void* d_out, int out_size, void* d_ws, size_t ws_size,
                              hipStream_t stream) {
    const float* h = (const float*)d_in[0];   // [8192, 4096] fp32
    const float* w = (const float*)d_in[1];   // [64, 4096] fp32
    float* out = (float*)d_out;               // topk_weight (65536 f32) ++ topk_idx (65536, written as float)

    moe_gate_kernel<<<NTOK / TOKB, 256, 0, stream>>>(h, w, out);
}